// Round 1
// baseline (655.719 us; speedup 1.0000x reference)
//
#include <hip/hip_runtime.h>
#include <hip/hip_bf16.h>

namespace {

typedef __attribute__((ext_vector_type(8))) short bf16x8;
typedef __attribute__((ext_vector_type(4))) float f32x4;

constexpr int kB = 8, kS = 64, kC = 16, kH = 64, kW = 64;
constexpr int kHC = 32, kHP = 62, kWP = 62;
constexpr int kPlane = kH * kW * kC;          // 65536 elements per (b,s) plane
constexpr int kPix = kHP * kWP;               // 3844
constexpr int kKpad = 160;                    // K=144 padded to 160

// ---------------- pre-pass 1: x [b][s][ic][h][w] fp32 -> x_t [b][s][h][w][ic] bf16
// float4 reads (1 KB/instr per wave), 128 B contiguous writes per thread.
__global__ __launch_bounds__(256)
void transpose_x(const float* __restrict__ x, __hip_bfloat16* __restrict__ xt)
{
    const size_t gi = (size_t)blockIdx.x * 256 + threadIdx.x;   // 0 .. 8*64*1024-1
    const size_t bs = gi >> 10;
    const int px0 = ((int)gi & 1023) << 2;                      // 4 pixels per thread
    const float* src = x + bs * (size_t)kPlane + px0;

    float4 v[16];
    #pragma unroll
    for (int ic = 0; ic < 16; ++ic)
        v[ic] = *reinterpret_cast<const float4*>(src + (size_t)ic * (kH * kW));

    union { unsigned short u[8]; uint4 q; } pk[8];              // 4 px * 16 ic bf16
    #pragma unroll
    for (int p = 0; p < 4; ++p) {
        #pragma unroll
        for (int ic = 0; ic < 16; ++ic) {
            const float f = reinterpret_cast<const float*>(&v[ic])[p];
            __hip_bfloat16 hb = __float2bfloat16(f);
            pk[p * 2 + (ic >> 3)].u[ic & 7] = *reinterpret_cast<unsigned short*>(&hb);
        }
    }
    uint4* dst = reinterpret_cast<uint4*>(xt + (bs * 4096 + (size_t)px0) * 16);
    #pragma unroll
    for (int j = 0; j < 8; ++j) dst[j] = pk[j].q;
}

// ---------------- pre-pass 2: W [oc][ic][3][3] fp32 -> Wk [oc][k] bf16, k = ky*48+kx*16+ic, pad to 160
__global__ __launch_bounds__(256)
void reorder_w(const float* __restrict__ wgt, __hip_bfloat16* __restrict__ wk)
{
    const int i = blockIdx.x * 256 + threadIdx.x;
    if (i >= 64 * kKpad) return;
    const int oc = i / kKpad, k = i % kKpad;
    float val = 0.f;
    if (k < 144) {
        const int ky = k / 48, r = k % 48, kx = r / 16, ic = r % 16;
        val = wgt[oc * 144 + ic * 9 + ky * 3 + kx];
    }
    wk[i] = __float2bfloat16(val);
}

// ---------------- main: fused MFMA conv + GRU scan.
// One wave = (b, py, 16-px tile, one (gate,hidden) tile-pair t), loops s with
// ping-pong-prefetched A fragments. Grid (62, 8, 2) -> 3968 waves (~3.9/SIMD).
__global__ __launch_bounds__(256, 4)
void conv_gru_mfma(const __hip_bfloat16* __restrict__ xt,
                   const __hip_bfloat16* __restrict__ wk,
                   const float* __restrict__ bias,
                   float* __restrict__ out)
{
    const int tid  = threadIdx.x;
    const int lane = tid & 63;
    const int wv   = tid >> 6;          // 0..3 -> px tile
    const int py   = blockIdx.x;        // 0..61
    const int b    = blockIdx.y;        // 0..7
    const int t    = blockIdx.z;        // 0..1 -> (gate tile t, hidden tile t+2)
    const int px0  = wv * 16;
    const int n    = lane & 15;         // A row m / B col n / D col n
    const int q    = lane >> 4;         // k-quad / D row group

    // ---- weight fragments for this pair only: 2 x 5 x 4 = 40 VGPRs, loaded once.
    bf16x8 wfG[5], wfH[5];
    #pragma unroll
    for (int c = 0; c < 5; ++c) {
        wfG[c] = *reinterpret_cast<const bf16x8*>(wk + (t * 16 + n) * kKpad + c * 32 + q * 8);
        wfH[c] = *reinterpret_cast<const bf16x8*>(wk + ((t + 2) * 16 + n) * kKpad + c * 32 + q * 8);
    }

    // ---- per-lane A-fragment element offsets within one (b,s) plane (constant over s)
    const int px_eff = (px0 + n > 61) ? 61 : (px0 + n);   // clamp keeps reads in-plane
    int aoff[5];
    #pragma unroll
    for (int c = 0; c < 5; ++c) {
        int k = c * 32 + q * 8;
        int ky, off;
        if (k >= 144) { ky = 2; off = 32; }               // pad chunk: W=0, address harmless
        else          { ky = k / 48; off = k % 48; }
        aoff[c] = (py + ky) * (kW * kC) + px_eff * kC + off;
    }

    const __hip_bfloat16* xb = xt + (size_t)b * kS * kPlane;
    const float bg = bias[t * 16 + n];
    const float bh = bias[32 + t * 16 + n];

    float h[4] = {0.5f, 0.5f, 0.5f, 0.5f};

    const int px_st = px0 + q * 4;                        // store base col (4 px per lane)
    const bool full4 = (px_st + 3 <= 61);

    float* op = out + (size_t)b * kS * kHC * kPix
                    + (size_t)(t * 16 + n) * kPix + (size_t)py * kWP + px_st;
    constexpr size_t sStride = (size_t)kHC * kPix;

    auto step = [&](const bf16x8 (&af)[5], float* p) {
        f32x4 a0 = {0.f, 0.f, 0.f, 0.f}, a1 = {0.f, 0.f, 0.f, 0.f};
        #pragma unroll
        for (int c = 0; c < 5; ++c) {
            a0 = __builtin_amdgcn_mfma_f32_16x16x32_bf16(af[c], wfG[c], a0, 0, 0, 0);
            a1 = __builtin_amdgcn_mfma_f32_16x16x32_bf16(af[c], wfH[c], a1, 0, 0, 0);
        }
        #pragma unroll
        for (int r = 0; r < 4; ++r) {
            const float gate = a0[r] + bg;
            const float hid  = a1[r] + bh;
            const float z  = __builtin_amdgcn_rcpf(1.f + __expf(-gate));   // fast sigmoid
            const float sg = __builtin_amdgcn_rcpf(1.f + __expf(-hid));
            const float gv = (hid >= 0.f) ? (hid + 0.5f) : sg;
            h[r] += z * (gv - h[r]);                       // (1-z)h + z*gv
        }
        if (full4) {
            f32x4 hv = {h[0], h[1], h[2], h[3]};
            __builtin_nontemporal_store(hv, reinterpret_cast<f32x4*>(p));
        } else {
            #pragma unroll
            for (int r = 0; r < 4; ++r)
                if (px_st + r <= 61) __builtin_nontemporal_store(h[r], p + r);
        }
    };

    // ---- software pipeline: prefetch s+1 while computing s (ping-pong, no copies)
    bf16x8 afA[5], afB[5];
    #pragma unroll
    for (int c = 0; c < 5; ++c)
        afA[c] = *reinterpret_cast<const bf16x8*>(xb + aoff[c]);

    for (int s = 0; s < kS; s += 2) {
        {
            const __hip_bfloat16* xn = xb + (size_t)(s + 1) * kPlane;
            #pragma unroll
            for (int c = 0; c < 5; ++c)
                afB[c] = *reinterpret_cast<const bf16x8*>(xn + aoff[c]);
            step(afA, op + (size_t)s * sStride);
        }
        {
            const int sp = (s + 2 < kS) ? (s + 2) : (kS - 1);
            const __hip_bfloat16* xn = xb + (size_t)sp * kPlane;
            #pragma unroll
            for (int c = 0; c < 5; ++c)
                afA[c] = *reinterpret_cast<const bf16x8*>(xn + aoff[c]);
            step(afB, op + (size_t)(s + 1) * sStride);
        }
    }

    // ---- h_final (h holds s=63 state)
    float* pf = out + (size_t)kB * kS * kHC * kPix + (size_t)b * kHC * kPix
                    + (size_t)(t * 16 + n) * kPix + (size_t)py * kWP + px_st;
    if (full4) {
        f32x4 hv = {h[0], h[1], h[2], h[3]};
        __builtin_nontemporal_store(hv, reinterpret_cast<f32x4*>(pf));
    } else {
        #pragma unroll
        for (int r = 0; r < 4; ++r)
            if (px_st + r <= 61) __builtin_nontemporal_store(h[r], pf + r);
    }
}

} // namespace

extern "C" void kernel_launch(void* const* d_in, const int* in_sizes, int n_in,
                              void* d_out, int out_size, void* d_ws, size_t ws_size,
                              hipStream_t stream)
{
    const float* x  = (const float*)d_in[0];
    const float* Wt = (const float*)d_in[1];
    const float* b  = (const float*)d_in[2];
    float* out = (float*)d_out;

    // workspace layout: Wk (64*160 bf16 = 20 KB, padded to 32 KB) | x_t (64 MB)
    __hip_bfloat16* wk = (__hip_bfloat16*)d_ws;
    __hip_bfloat16* xt = (__hip_bfloat16*)((char*)d_ws + 32768);

    reorder_w<<<dim3((64 * kKpad + 255) / 256), dim3(256), 0, stream>>>(Wt, wk);
    transpose_x<<<dim3(kB * kS * kH * kW / 4 / 256), dim3(256), 0, stream>>>(x, xt);
    conv_gru_mfma<<<dim3(kHP, kB, 2), dim3(256), 0, stream>>>(xt, wk, b, out);
}

// Round 2
// 483.150 us; speedup vs baseline: 1.3572x; 1.3572x over previous
//
#include <hip/hip_runtime.h>
#include <hip/hip_bf16.h>

namespace {

typedef __attribute__((ext_vector_type(8))) short bf16x8;
typedef __attribute__((ext_vector_type(4))) float f32x4;

constexpr int kB = 8, kS = 64, kC = 16, kH = 64, kW = 64;
constexpr int kHC = 32, kHP = 62, kWP = 62;
constexpr int kPlane = kH * kW * kC;          // 65536 elements per (b,s) plane
constexpr int kPix = kHP * kWP;               // 3844
constexpr int kKpad = 160;                    // K=144 padded to 160

// ---------------- pre-pass 1: x [b][s][ic][h][w] fp32 -> x_t [b][s][h][w][ic] bf16
__global__ __launch_bounds__(256)
void transpose_x(const float* __restrict__ x, __hip_bfloat16* __restrict__ xt)
{
    const size_t gi = (size_t)blockIdx.x * 256 + threadIdx.x;   // 0 .. 8*64*1024-1
    const size_t bs = gi >> 10;
    const int px0 = ((int)gi & 1023) << 2;                      // 4 pixels per thread
    const float* src = x + bs * (size_t)kPlane + px0;

    float4 v[16];
    #pragma unroll
    for (int ic = 0; ic < 16; ++ic)
        v[ic] = *reinterpret_cast<const float4*>(src + (size_t)ic * (kH * kW));

    union { unsigned short u[8]; uint4 q; } pk[8];              // 4 px * 16 ic bf16
    #pragma unroll
    for (int p = 0; p < 4; ++p) {
        #pragma unroll
        for (int ic = 0; ic < 16; ++ic) {
            const float f = reinterpret_cast<const float*>(&v[ic])[p];
            __hip_bfloat16 hb = __float2bfloat16(f);
            pk[p * 2 + (ic >> 3)].u[ic & 7] = *reinterpret_cast<unsigned short*>(&hb);
        }
    }
    uint4* dst = reinterpret_cast<uint4*>(xt + (bs * 4096 + (size_t)px0) * 16);
    #pragma unroll
    for (int j = 0; j < 8; ++j) dst[j] = pk[j].q;
}

// ---------------- pre-pass 2: W [oc][ic][3][3] fp32 -> Wk [oc][k] bf16, k = ky*48+kx*16+ic, pad to 160
__global__ __launch_bounds__(256)
void reorder_w(const float* __restrict__ wgt, __hip_bfloat16* __restrict__ wk)
{
    const int i = blockIdx.x * 256 + threadIdx.x;
    if (i >= 64 * kKpad) return;
    const int oc = i / kKpad, k = i % kKpad;
    float val = 0.f;
    if (k < 144) {
        const int ky = k / 48, r = k % 48, kx = r / 16, ic = r % 16;
        val = wgt[oc * 144 + ic * 9 + ky * 3 + kx];
    }
    wk[i] = __float2bfloat16(val);
}

// ---------------- main: fused MFMA conv + GRU scan.
// One wave = (b, py, 16-px tile), all 4 oc-tiles, loops s with ping-pong prefetch.
// Grid is linear 496 with b = blockIdx.x & 7: all blocks of a batch land on ONE XCD,
// so the current (b,s) xt plane (128 KB) stays L2-resident -> af loads are L2 hits.
__global__ __launch_bounds__(256, 2)
void conv_gru_mfma(const __hip_bfloat16* __restrict__ xt,
                   const __hip_bfloat16* __restrict__ wk,
                   const float* __restrict__ bias,
                   float* __restrict__ out)
{
    const int tid  = threadIdx.x;
    const int lane = tid & 63;
    const int wv   = tid >> 6;          // 0..3 -> px tile
    const int lin  = blockIdx.x;        // 0..495
    const int b    = lin & 7;           // XCD-pinned batch
    const int py   = lin >> 3;          // 0..61
    const int px0  = wv * 16;
    const int n    = lane & 15;         // A row m / B col n / D col n
    const int q    = lane >> 4;         // k-quad / D row group

    // ---- weight fragments wf[t][c]: volatile loads -> must stay register-resident
    // (80 VGPRs; round-0's VGPR_Count=72 proved the compiler was re-loading these
    //  every s-step otherwise)
    bf16x8 wf[4][5];
    #pragma unroll
    for (int t = 0; t < 4; ++t)
        #pragma unroll
        for (int c = 0; c < 5; ++c)
            wf[t][c] = *reinterpret_cast<const volatile bf16x8*>(
                wk + (t * 16 + n) * kKpad + c * 32 + q * 8);

    // ---- per-lane A-fragment element offsets within one (b,s) plane (constant over s)
    const int px_eff = (px0 + n > 61) ? 61 : (px0 + n);   // clamp keeps reads in-plane
    int aoff[5];
    #pragma unroll
    for (int c = 0; c < 5; ++c) {
        int k = c * 32 + q * 8;
        int ky, off;
        if (k >= 144) { ky = 2; off = 32; }               // pad chunk: W=0, address harmless
        else          { ky = k / 48; off = k % 48; }
        aoff[c] = (py + ky) * (kW * kC) + px_eff * kC + off;
    }

    const __hip_bfloat16* xb = xt + (size_t)b * kS * kPlane;
    const float bg[2] = { bias[n],      bias[16 + n] };
    const float bh[2] = { bias[32 + n], bias[48 + n] };

    float h[2][4];
    #pragma unroll
    for (int t = 0; t < 2; ++t)
        #pragma unroll
        for (int r = 0; r < 4; ++r) h[t][r] = 0.5f;

    const int px_st = px0 + q * 4;                        // store base col (4 px per lane)
    const bool full4 = (px_st + 3 <= 61);

    float* outh = out + (size_t)b * kS * kHC * kPix + (size_t)py * kWP;
    float* outf = out + (size_t)kB * kS * kHC * kPix + (size_t)b * kHC * kPix
                      + (size_t)py * kWP;

    auto step = [&](const bf16x8 (&af)[5], int s) {
        f32x4 acc[4];
        #pragma unroll
        for (int t = 0; t < 4; ++t) acc[t] = (f32x4){0.f, 0.f, 0.f, 0.f};

        #pragma unroll
        for (int c = 0; c < 5; ++c)
            #pragma unroll
            for (int t = 0; t < 4; ++t)
                acc[t] = __builtin_amdgcn_mfma_f32_16x16x32_bf16(af[c], wf[t][c], acc[t], 0, 0, 0);

        float* os = outh + (size_t)s * (kHC * kPix);
        #pragma unroll
        for (int t = 0; t < 2; ++t) {
            #pragma unroll
            for (int r = 0; r < 4; ++r) {
                const float gate = acc[t][r]     + bg[t];
                const float hid  = acc[t + 2][r] + bh[t];
                const float z  = __builtin_amdgcn_rcpf(1.f + __expf(-gate));  // fast sigmoid
                const float sg = __builtin_amdgcn_rcpf(1.f + __expf(-hid));
                const float gv = (hid >= 0.f) ? (hid + 0.5f) : sg;
                h[t][r] += z * (gv - h[t][r]);             // (1-z)h + z*gv
            }
            float* p = os + (t * 16 + n) * kPix + px_st;
            if (full4) {
                *reinterpret_cast<float4*>(p) = make_float4(h[t][0], h[t][1], h[t][2], h[t][3]);
            } else {
                #pragma unroll
                for (int r = 0; r < 4; ++r)
                    if (px_st + r <= 61) p[r] = h[t][r];
            }
            if (s == kS - 1) {
                float* pf = outf + (t * 16 + n) * kPix + px_st;
                if (full4) {
                    *reinterpret_cast<float4*>(pf) = make_float4(h[t][0], h[t][1], h[t][2], h[t][3]);
                } else {
                    #pragma unroll
                    for (int r = 0; r < 4; ++r)
                        if (px_st + r <= 61) pf[r] = h[t][r];
                }
            }
        }
    };

    // ---- software pipeline: prefetch s+1 while computing s (ping-pong, no copies)
    bf16x8 afA[5], afB[5];
    #pragma unroll
    for (int c = 0; c < 5; ++c)
        afA[c] = *reinterpret_cast<const bf16x8*>(xb + aoff[c]);

    for (int s = 0; s < kS; s += 2) {
        const __hip_bfloat16* x1 = xb + (size_t)(s + 1) * kPlane;
        #pragma unroll
        for (int c = 0; c < 5; ++c)
            afB[c] = *reinterpret_cast<const bf16x8*>(x1 + aoff[c]);
        step(afA, s);

        const int sp = (s + 2 < kS) ? (s + 2) : (kS - 1);
        const __hip_bfloat16* x2 = xb + (size_t)sp * kPlane;
        #pragma unroll
        for (int c = 0; c < 5; ++c)
            afA[c] = *reinterpret_cast<const bf16x8*>(x2 + aoff[c]);
        step(afB, s + 1);
    }
}

} // namespace

extern "C" void kernel_launch(void* const* d_in, const int* in_sizes, int n_in,
                              void* d_out, int out_size, void* d_ws, size_t ws_size,
                              hipStream_t stream)
{
    const float* x  = (const float*)d_in[0];
    const float* Wt = (const float*)d_in[1];
    const float* b  = (const float*)d_in[2];
    float* out = (float*)d_out;

    // workspace layout: Wk (64*160 bf16 = 20 KB, padded to 32 KB) | x_t (64 MB)
    __hip_bfloat16* wk = (__hip_bfloat16*)d_ws;
    __hip_bfloat16* xt = (__hip_bfloat16*)((char*)d_ws + 32768);

    reorder_w<<<dim3((64 * kKpad + 255) / 256), dim3(256), 0, stream>>>(Wt, wk);
    transpose_x<<<dim3(kB * kS * kH * kW / 4 / 256), dim3(256), 0, stream>>>(x, xt);
    conv_gru_mfma<<<dim3(kHP * kB), dim3(256), 0, stream>>>(xt, wk, b, out);
}